// Round 12
// baseline (2317.235 us; speedup 1.0000x reference)
//
#include <hip/hip_runtime.h>

#define KC 256
#define DIM 64
#define NITER 10
#define SB 64      // sum2 batch rows

typedef __attribute__((ext_vector_type(16))) float f32x16;

// numpy pairwise sum for 64 elements, inputs already rounded f32:
// r[j] = a[j]+a[j+8]+...+a[j+56] (sequential), then ((r0+r1)+(r2+r3))+((r4+r5)+(r6+r7))
__device__ __forceinline__ float np_pairwise_sq64(const float* a) {
    float r[8];
#pragma unroll
    for (int j = 0; j < 8; ++j) r[j] = __fmul_rn(a[j], a[j]);
#pragma unroll
    for (int i = 8; i < 64; i += 8)
#pragma unroll
        for (int j = 0; j < 8; ++j)
            r[j] = __fadd_rn(r[j], __fmul_rn(a[i + j], a[i + j]));
    float t01 = __fadd_rn(r[0], r[1]), t23 = __fadd_rn(r[2], r[3]);
    float t45 = __fadd_rn(r[4], r[5]), t67 = __fadd_rn(r[6], r[7]);
    return __fadd_rn(__fadd_rn(t01, t23), __fadd_rn(t45, t67));
}

// ---------------- init: c = x[:K] ----------------
__global__ void init_k(const float* __restrict__ x, float* __restrict__ c) {
    const int idx = blockIdx.x * 256 + threadIdx.x;
    if (idx < KC * DIM) c[idx] = x[idx];
}

// ---------------- csqg: csq_g[k] = numpy-pairwise ||c_k||^2 (global), first-NaN index ----------------
__global__ __launch_bounds__(256) void csqg_k(
    const float* __restrict__ c, float* __restrict__ csq_g, int* __restrict__ nan_g)
{
    const int k = threadIdx.x;
    if (k == 0) *nan_g = 0x7fffffff;
    __syncthreads();
    float cr[DIM];
    const float4* cp = reinterpret_cast<const float4*>(c + k * DIM);
#pragma unroll
    for (int j = 0; j < DIM / 4; ++j) {
        float4 v = cp[j];
        cr[4 * j + 0] = v.x; cr[4 * j + 1] = v.y;
        cr[4 * j + 2] = v.z; cr[4 * j + 3] = v.w;
    }
    const float s = np_pairwise_sq64(cr);
    csq_g[k] = s;
    if (s != s) atomicMin(nan_g, k);   // dist NaN <=> csq NaN; numpy argmin: first NaN wins
}

// ---------------- assign: c via SGPR s_load (scalar pipe), exact f32 chain on VALU ----------------
__global__ __launch_bounds__(256) void assign_hist_k(
    const float* __restrict__ x, const float* __restrict__ c,
    const float* __restrict__ csq_g, const int* __restrict__ nan_g,
    float* __restrict__ labels, int* __restrict__ hist, int n)
{
    __shared__ int whist[4 * KC];
    const int t = threadIdx.x;
    for (int j = t; j < 4 * KC; j += 256) whist[j] = 0;

    const int i = blockIdx.x * 256 + t;
    const bool valid = (i < n);

    float xr[DIM];
    const float4* xv = reinterpret_cast<const float4*>(x + (size_t)(valid ? i : 0) * DIM);
#pragma unroll
    for (int j = 0; j < DIM / 4; ++j) {
        float4 v = xv[j];
        xr[4 * j + 0] = v.x; xr[4 * j + 1] = v.y;
        xr[4 * j + 2] = v.z; xr[4 * j + 3] = v.w;
    }
    const float xsq = np_pairwise_sq64(xr);
    const int firstNan = *nan_g;                     // uniform, L2-hot

    float best = __int_as_float(0x7f800000);
    int bk = 0;

#pragma unroll 1
    for (int k = 0; k < KC; ++k) {
        f32x16 h0, h1, h2, h3;
        float cs;
        const float* rp = c + (size_t)k * DIM;       // wave-uniform row pointer
        asm volatile("s_load_dwordx16 %0, %1, 0x0"  : "=s"(h0) : "s"(rp));
        asm volatile("s_load_dwordx16 %0, %1, 0x40" : "=s"(h1) : "s"(rp));
        asm volatile("s_load_dwordx16 %0, %1, 0x80" : "=s"(h2) : "s"(rp));
        asm volatile("s_load_dwordx16 %0, %1, 0xc0" : "=s"(h3) : "s"(rp));
        asm volatile("s_load_dword %0, %1, 0x0"     : "=s"(cs) : "s"(csq_g + k));
        // SMEM returns out-of-order: full drain; "+s" ties order the FMAs after the wait
        asm volatile("s_waitcnt lgkmcnt(0)"
                     : "+s"(h0), "+s"(h1), "+s"(h2), "+s"(h3), "+s"(cs));

        float acc = 0.0f;                            // exact ascending-d FMA chain
#pragma unroll
        for (int d = 0; d < 16; ++d) acc = fmaf(xr[d],      h0[d], acc);
#pragma unroll
        for (int d = 0; d < 16; ++d) acc = fmaf(xr[16 + d], h1[d], acc);
#pragma unroll
        for (int d = 0; d < 16; ++d) acc = fmaf(xr[32 + d], h2[d], acc);
#pragma unroll
        for (int d = 0; d < 16; ++d) acc = fmaf(xr[48 + d], h3[d], acc);

        // (xsq - 2*acc) + csq : fmaf(-2,acc,xsq) rounds the same exact value once
        const float dist = __fadd_rn(fmaf(-2.0f, acc, xsq), cs);
        if (dist < best) { best = dist; bk = k; }
    }

    int lbl = 0;
    if (valid) {
        lbl = (firstNan != 0x7fffffff) ? firstNan : bk;
        labels[i] = (float)lbl;
    }

    __syncthreads();   // whist zeros visible
    const int lane = t & 63, w = t >> 6;
    unsigned long long same = __ballot(valid);
#pragma unroll
    for (int bit = 0; bit < 8; ++bit) {
        unsigned long long bb = __ballot((lbl >> bit) & 1);
        same &= ((lbl >> bit) & 1) ? bb : ~bb;
    }
    if (valid && lane == __builtin_ctzll(same))
        whist[w * KC + lbl] = (int)__popcll(same);
    __syncthreads();
    if (t < KC)
        hist[(size_t)blockIdx.x * KC + t] =
            whist[t] + whist[KC + t] + whist[2 * KC + t] + whist[3 * KC + t];
}

// ---------------- scan1: per-cluster exclusive prefix over blocks ----------------
__global__ __launch_bounds__(256) void scan1_k(
    int* __restrict__ hist, int nb, int* __restrict__ cnt)
{
    __shared__ int sbuf[256];
    const int k = blockIdx.x;
    const int t = threadIdx.x;
    const int epb = (nb + 255) / 256;
    const int b0 = t * epb;

    int s = 0;
    for (int u = 0; u < epb; ++u) {
        const int b = b0 + u;
        if (b < nb) s += hist[(size_t)b * KC + k];
    }
    sbuf[t] = s;
    __syncthreads();
    int incl = s;
#pragma unroll
    for (int d = 1; d < 256; d <<= 1) {
        const int v = (t >= d) ? sbuf[t - d] : 0;
        __syncthreads();
        incl += v;
        sbuf[t] = incl;
        __syncthreads();
    }
    int run = incl - s;
    for (int u = 0; u < epb; ++u) {
        const int b = b0 + u;
        if (b < nb) {
            const int v = hist[(size_t)b * KC + k];
            hist[(size_t)b * KC + k] = run;
            run += v;
        }
    }
    if (t == 255) cnt[k] = incl;
}

// ---------------- scan2: cluster bases (padded to 64 rows) ----------------
__global__ __launch_bounds__(256) void scan2_k(
    const int* __restrict__ cnt, int* __restrict__ base)
{
    __shared__ int sbuf[256];
    const int t = threadIdx.x;
    const int padded = (cnt[t] + 63) & ~63;
    sbuf[t] = padded;
    __syncthreads();
    int incl = padded;
#pragma unroll
    for (int d = 1; d < 256; d <<= 1) {
        const int v = (t >= d) ? sbuf[t - d] : 0;
        __syncthreads();
        incl += v;
        sbuf[t] = incl;
        __syncthreads();
    }
    base[t] = incl - padded;
}

// ---------------- scatter2: stable counting-sort placement fused with row copy ----------------
__global__ __launch_bounds__(256) void scatter2_k(
    const float* __restrict__ x, const float* __restrict__ labels,
    const int* __restrict__ hist, const int* __restrict__ base,
    float* __restrict__ xs, int n)
{
    __shared__ int whist[4 * KC];
    const int t = threadIdx.x;
    for (int j = t; j < 4 * KC; j += 256) whist[j] = 0;
    __syncthreads();

    const int i = blockIdx.x * 256 + t;
    const bool valid = (i < n);
    const int lbl = valid ? (int)labels[i] : 0;
    const int lane = t & 63, w = t >> 6;

    unsigned long long same = __ballot(valid);
#pragma unroll
    for (int bit = 0; bit < 8; ++bit) {
        unsigned long long bb = __ballot((lbl >> bit) & 1);
        same &= ((lbl >> bit) & 1) ? bb : ~bb;
    }
    const unsigned long long below = (1ull << lane) - 1ull;
    const int rank_wave = (int)__popcll(same & below);
    if (valid && lane == __builtin_ctzll(same))
        whist[w * KC + lbl] = (int)__popcll(same);
    __syncthreads();

    if (valid) {
        int off = rank_wave;
        for (int ww = 0; ww < w; ++ww) off += whist[ww * KC + lbl];
        const int pos = base[lbl] + hist[(size_t)blockIdx.x * KC + lbl] + off;
        const float4* src = reinterpret_cast<const float4*>(x + (size_t)i * DIM);
        float4* dst = reinterpret_cast<float4*>(xs + (size_t)pos * DIM);
#pragma unroll
        for (int j = 0; j < DIM / 4; ++j) dst[j] = src[j];
    }
}

// ---------------- padzero: zero segment tails (exact no-op adds in sum2) ----------------
__global__ __launch_bounds__(64) void padzero_k(
    float* __restrict__ xs, const int* __restrict__ base, const int* __restrict__ cnt)
{
    const int k = blockIdx.x;
    const int lane = threadIdx.x;
    const int b0 = base[k];
    const int ct = cnt[k];
    const int ctp = (ct + 63) & ~63;
    for (int r = ct; r < ctp; ++r)
        xs[(size_t)(b0 + r) * DIM + lane] = 0.0f;
}

// ---------------- sum2: sequential coalesced stream, 3-buffer pipelined exact f32 chain ----------------
#define LB(dst, off)                                                        \
    _Pragma("unroll")                                                       \
    for (int u = 0; u < SB; ++u) dst[u] = s[(size_t)((off) + u) * DIM];
#define AB(src)                                                             \
    _Pragma("unroll")                                                       \
    for (int u = 0; u < SB; ++u) acc = __fadd_rn(acc, src[u]);

__global__ __launch_bounds__(64) void sum2_k(
    const float* __restrict__ xs, const int* __restrict__ base,
    const int* __restrict__ cnt, float* __restrict__ c)
{
    const int k = blockIdx.x;
    const int lane = threadIdx.x;                 // = dim
    const int b0 = base[k];                       // multiple of 64
    const int ct = cnt[k];
    const int ctp = (ct + 63) & ~63;              // padded row count (zeros at tail)
    const float* s = xs + (size_t)b0 * DIM + lane;

    float va[SB], vb[SB], vc[SB];
    float acc = 0.0f;

    if (ctp >= 2 * SB) {
        LB(va, 0)
        LB(vb, SB)
        int j = 0;
        for (; j + 5 * SB <= ctp; j += 3 * SB) {
            LB(vc, j + 2 * SB)
            AB(va)
            LB(va, j + 3 * SB)
            AB(vb)
            LB(vb, j + 4 * SB)
            AB(vc)
        }
        const int rem = ctp - j;                  // 2*SB, 3*SB, or 4*SB
        AB(va)
        AB(vb)
        if (rem >= 3 * SB) {
            LB(vc, j + 2 * SB)
            AB(vc)
        }
        if (rem >= 4 * SB) {
            LB(va, j + 3 * SB)
            AB(va)
        }
    } else if (ctp == SB) {
        LB(va, 0)
        AB(va)
    }
    c[k * DIM + lane] = __fdiv_rn(acc, (float)ct);   // 0/0 -> NaN matches ref
}

// ---------------- fallback: old scatter (order) + gather (used only if d_ws too small) ----------------
__global__ __launch_bounds__(256) void scatter_k(
    const float* __restrict__ labels, const int* __restrict__ hist,
    const int* __restrict__ base, int* __restrict__ order, int n)
{
    __shared__ int whist[4 * KC];
    const int t = threadIdx.x;
    for (int j = t; j < 4 * KC; j += 256) whist[j] = 0;
    __syncthreads();

    const int i = blockIdx.x * 256 + t;
    const bool valid = (i < n);
    const int lbl = valid ? (int)labels[i] : 0;
    const int lane = t & 63, w = t >> 6;

    unsigned long long same = __ballot(valid);
#pragma unroll
    for (int bit = 0; bit < 8; ++bit) {
        unsigned long long bb = __ballot((lbl >> bit) & 1);
        same &= ((lbl >> bit) & 1) ? bb : ~bb;
    }
    const unsigned long long below = (1ull << lane) - 1ull;
    const int rank_wave = (int)__popcll(same & below);
    if (valid && lane == __builtin_ctzll(same))
        whist[w * KC + lbl] = (int)__popcll(same);
    __syncthreads();

    if (valid) {
        int off = rank_wave;
        for (int ww = 0; ww < w; ++ww) off += whist[ww * KC + lbl];
        const int pos = base[lbl] + hist[(size_t)blockIdx.x * KC + lbl] + off;
        order[pos] = i;
    }
}

__global__ __launch_bounds__(64) void gather_k(
    const float* __restrict__ x, const int* __restrict__ order,
    const int* __restrict__ base, const int* __restrict__ cnt,
    float* __restrict__ c)
{
    const int k = blockIdx.x;
    const int lane = threadIdx.x;
    const int b0 = base[k];
    const int ct = cnt[k];
    float acc = 0.0f;
    int j = 0;
    for (; j + 32 <= ct; j += 32) {
        float v[32];
#pragma unroll
        for (int u = 0; u < 32; ++u)
            v[u] = x[(size_t)order[b0 + j + u] * DIM + lane];
#pragma unroll
        for (int u = 0; u < 32; ++u) acc = __fadd_rn(acc, v[u]);
    }
    for (; j < ct; ++j)
        acc = __fadd_rn(acc, x[(size_t)order[b0 + j] * DIM + lane]);
    c[k * DIM + lane] = __fdiv_rn(acc, (float)ct);
}

extern "C" void kernel_launch(void* const* d_in, const int* in_sizes, int n_in,
                              void* d_out, int out_size, void* d_ws, size_t ws_size,
                              hipStream_t stream)
{
    const float* x = (const float*)d_in[0];
    const int n = in_sizes[0] / DIM;          // 262144

    float* out_c = (float*)d_out;             // [256*64] centroids (working buffer too)
    float* out_labels = out_c + KC * DIM;     // [n] labels as floats

    const int nb = (n + 255) / 256;           // 1024 blocks of 256 points
    const int nstride = n + KC * 64;          // padded sorted-position capacity

    // workspace layout (256B-aligned blocks)
    size_t off = 0;
    auto alloc = [&](size_t bytes) -> size_t {
        size_t o = off; off = (off + bytes + 255) & ~(size_t)255; return o;
    };
    char*  w     = (char*)d_ws;
    float* csq_g = (float*)(w + alloc(KC * sizeof(float)));
    int*   nan_g = (int*)(w + alloc(256));
    int*   hist  = (int*)(w + alloc((size_t)nb * KC * sizeof(int)));
    int*   base  = (int*)(w + alloc(KC * sizeof(int)));
    int*   cnt   = (int*)(w + alloc(KC * sizeof(int)));
    int*   order = (int*)(w + alloc((size_t)nstride * sizeof(int)));
    const size_t med_need = off;
    float* xs    = (float*)(w + alloc((size_t)nstride * DIM * sizeof(float)));
    const size_t big_need = off;

    const bool big = (ws_size >= big_need);
    const bool med = (ws_size >= med_need);

    init_k<<<(KC * DIM + 255) / 256, 256, 0, stream>>>(x, out_c);

    for (int it = 0; it < NITER; ++it) {
        csqg_k<<<1, 256, 0, stream>>>(out_c, csq_g, nan_g);
        assign_hist_k<<<nb, 256, 0, stream>>>(x, out_c, csq_g, nan_g, out_labels, hist, n);
        if (med) {
            scan1_k<<<KC, 256, 0, stream>>>(hist, nb, cnt);
            scan2_k<<<1, 256, 0, stream>>>(cnt, base);
            if (big) {
                scatter2_k<<<nb, 256, 0, stream>>>(x, out_labels, hist, base, xs, n);
                padzero_k<<<KC, 64, 0, stream>>>(xs, base, cnt);
                sum2_k<<<KC, 64, 0, stream>>>(xs, base, cnt, out_c);
            } else {
                scatter_k<<<nb, 256, 0, stream>>>(out_labels, hist, base, order, n);
                gather_k<<<KC, 64, 0, stream>>>(x, order, base, cnt, out_c);
            }
        }
    }
}